// Round 6
// baseline (590.313 us; speedup 1.0000x reference)
//
#include <hip/hip_runtime.h>
#include <hip/hip_bf16.h>

// Problem constants (B=1)
#define SEQ   2048
#define DM    4096
#define NH    32
#define NKVH  8
#define HD    128
#define NQKV  6144
#define KOFF  4096
#define VOFF  5120
#define SCALE 0.08838834764831845f

typedef __attribute__((ext_vector_type(4))) float f32x4;
typedef __attribute__((ext_vector_type(8))) short short8;

__device__ __forceinline__ unsigned short f2bf(float f) {
  union { float f; unsigned int u; } v; v.f = f;
  unsigned int r = v.u + 0x7FFF + ((v.u >> 16) & 1);
  return (unsigned short)(r >> 16);
}
__device__ __forceinline__ float bf2f(unsigned short b) {
  union { unsigned int u; float f; } v; v.u = ((unsigned int)b) << 16;
  return v.f;
}

// async global->LDS, 16B per lane; LDS dest = wave-uniform base + lane*16
__device__ __forceinline__ void gld16(const unsigned short* g, unsigned short* l) {
  __builtin_amdgcn_global_load_lds(
      (const __attribute__((address_space(1))) unsigned int*)g,
      (__attribute__((address_space(3))) unsigned int*)l, 16, 0, 0);
}

// ---------------- fused prep: hs cast (blocks 0..8191) + weight transpose ----------------
__global__ __launch_bounds__(256) void prep(const float* __restrict__ hs,
                                            const float* __restrict__ wq,
                                            const float* __restrict__ wk,
                                            const float* __restrict__ wv,
                                            const float* __restrict__ wo,
                                            unsigned short* __restrict__ hsb,
                                            unsigned short* __restrict__ wqkvT,
                                            unsigned short* __restrict__ woT) {
  __shared__ unsigned short t[64][68];
  const int bxg = blockIdx.x;
  const int tid = threadIdx.x;
  if (bxg < 8192) {                       // ---- cast hs fp32 -> bf16 ----
    size_t i = ((size_t)bxg * 256 + tid) * 4;
    float4 v = *(const float4*)(hs + i);
    ushort4 o;
    o.x = f2bf(v.x); o.y = f2bf(v.y); o.z = f2bf(v.z); o.w = f2bf(v.w);
    *(ushort4*)(hsb + i) = o;
    return;
  }
  // ---- weight transpose+cast, 64x64 tiles ----
  const int b  = bxg - 8192;
  const int bx = b % 160;                 // tile-col group
  const int k0 = (b / 160) * 64;          // k tile
  const float* W; unsigned short* out; int N, n0, row_off;
  if (bx < 64)      { W = wq; out = wqkvT; N = 4096; n0 = bx * 64;        row_off = 0;    }
  else if (bx < 80) { W = wk; out = wqkvT; N = 1024; n0 = (bx - 64) * 64; row_off = 4096; }
  else if (bx < 96) { W = wv; out = wqkvT; N = 1024; n0 = (bx - 80) * 64; row_off = 5120; }
  else              { W = wo; out = woT;   N = 4096; n0 = (bx - 96) * 64; row_off = 0;    }

  const int lr = tid >> 4, lc = (tid & 15) * 4;
#pragma unroll
  for (int i = 0; i < 4; ++i) {
    float4 v = *(const float4*)&W[(size_t)(k0 + lr + i * 16) * N + n0 + lc];
    ushort4 u; u.x = f2bf(v.x); u.y = f2bf(v.y); u.z = f2bf(v.z); u.w = f2bf(v.w);
    *(ushort4*)&t[lr + i * 16][lc] = u;
  }
  __syncthreads();

  const int sn = tid >> 2, sk = (tid & 3) * 4;
#pragma unroll
  for (int i = 0; i < 4; ++i) {
    int kk = sk + i * 16;
    ushort4 u;
    u.x = t[kk + 0][sn]; u.y = t[kk + 1][sn];
    u.z = t[kk + 2][sn]; u.w = t[kk + 3][sn];
    *(ushort4*)&out[(size_t)(row_off + n0 + sn) * DM + k0 + kk] = u;
  }
}

// ---------------- GEMM: C[M,N] = A[M,K] @ Bt[N,K]^T ----------------
// 64x128 (MxN) tile, BK=32, double-buffered gld16. Small tile -> 2x blocks ->
// ~6 blocks/CU co-resident (LDS 24KB, VGPR<=85 via launch_bounds(256,6)) so
// the vmcnt(0) barrier drain is hidden by other blocks' MFMA (TLP, not SWP).
__global__ __launch_bounds__(256, 6) void gemm_bt(const unsigned short* __restrict__ A,
                                                  const unsigned short* __restrict__ Bt,
                                                  void* __restrict__ C,
                                                  int M, int N, int K, int c_fp32) {
  __shared__ unsigned short As[2][64 * 32];
  __shared__ unsigned short Bs[2][128 * 32];
  const int tid  = threadIdx.x;
  const int m0   = blockIdx.y * 64;
  const int n0   = blockIdx.x * 128;
  const int w    = tid >> 6;
  const int lane = tid & 63;
  const int l16  = lane & 15;
  const int quad = lane >> 4;
  const int wr   = (w >> 1) * 32;     // wave tile: 32 rows x 64 cols
  const int wc   = (w & 1) * 64;

  f32x4 acc[2][4];
#pragma unroll
  for (int i = 0; i < 2; ++i)
#pragma unroll
    for (int j = 0; j < 4; ++j) acc[i][j] = (f32x4){0.f, 0.f, 0.f, 0.f};

  // staging: 4 consecutive lanes cover one row's 64B k-slice (coalesced);
  // k-block XOR-permuted per row so LDS frag reads spread banks
  const int sr  = lane >> 2;
  const int pb  = lane & 3;
  const int sws = (sr & 3) ^ ((sr >> 2) & 3);
  const int kb  = ((pb ^ sws) << 3);
  const unsigned short* ga  = A  + (size_t)(m0 + w * 16 + sr) * K + kb;        // 16 A rows/wave
  const unsigned short* gb0 = Bt + (size_t)(n0 + w * 32 + sr) * K + kb;        // 32 B rows/wave
  const unsigned short* gb1 = Bt + (size_t)(n0 + w * 32 + 16 + sr) * K + kb;
  const int laofs  = (w * 16) * 32;
  const int lbofs0 = (w * 32) * 32;
  const int lbofs1 = (w * 32 + 16) * 32;

  const int swf  = (l16 & 3) ^ ((l16 >> 2) & 3);
  const int fcol = ((quad ^ swf) << 3);

  // prologue: stage tile 0 into buffer 0
  gld16(ga,  &As[0][laofs]);
  gld16(gb0, &Bs[0][lbofs0]);
  gld16(gb1, &Bs[0][lbofs1]);

  int p = 0;
  for (int k0 = 0; k0 < K; k0 += 32) {
    __syncthreads();            // drains vmcnt -> buf p visible; buf p^1 WAR-safe
    if (k0 + 32 < K) {          // next tile into buf p^1 (hidden behind MFMA + other blocks)
      gld16(ga  + k0 + 32, &As[p ^ 1][laofs]);
      gld16(gb0 + k0 + 32, &Bs[p ^ 1][lbofs0]);
      gld16(gb1 + k0 + 32, &Bs[p ^ 1][lbofs1]);
    }
    short8 af[2], bfr[4];
#pragma unroll
    for (int mt = 0; mt < 2; ++mt)
      af[mt] = *(const short8*)&As[p][(wr + mt * 16 + l16) * 32 + fcol];
#pragma unroll
    for (int nt = 0; nt < 4; ++nt)
      bfr[nt] = *(const short8*)&Bs[p][(wc + nt * 16 + l16) * 32 + fcol];
#pragma unroll
    for (int mt = 0; mt < 2; ++mt)
#pragma unroll
      for (int nt = 0; nt < 4; ++nt)
        acc[mt][nt] = __builtin_amdgcn_mfma_f32_16x16x32_bf16(af[mt], bfr[nt], acc[mt][nt], 0, 0, 0);
    p ^= 1;
  }

  if (c_fp32) {
    float* Cf = (float*)C;
#pragma unroll
    for (int mt = 0; mt < 2; ++mt)
#pragma unroll
      for (int nt = 0; nt < 4; ++nt) {
        int col = n0 + wc + nt * 16 + l16;
#pragma unroll
        for (int r = 0; r < 4; ++r)
          Cf[(size_t)(m0 + wr + mt * 16 + quad * 4 + r) * N + col] = acc[mt][nt][r];
      }
  } else {
    unsigned short* Cb = (unsigned short*)C;
#pragma unroll
    for (int mt = 0; mt < 2; ++mt)
#pragma unroll
      for (int nt = 0; nt < 4; ++nt) {
        int col = n0 + wc + nt * 16 + l16;
#pragma unroll
        for (int r = 0; r < 4; ++r)
          Cb[(size_t)(m0 + wr + mt * 16 + quad * 4 + r) * N + col] = f2bf(acc[mt][nt][r]);
      }
  }
}

// ---------------- fused RoPE (blocks 0..20479) + V transpose ----------------
// rope touches qkv cols [0,5120) (Q+K heads); v_transpose reads cols [5120,6144) -> disjoint.
__global__ __launch_bounds__(256) void rope_vt(unsigned short* __restrict__ QKV,
                                               const float* __restrict__ cosb,
                                               const float* __restrict__ sinb,
                                               unsigned short* __restrict__ Vt_g) {
  const int bxg = blockIdx.x;
  const int tid = threadIdx.x;
  if (bxg < 20480) {                      // ---- RoPE ----
    int idx = bxg * 256 + tid;
    int i = idx & 63;
    int h = (idx >> 6) % 40;
    int s = idx / 2560;
    size_t base = (size_t)s * NQKV + (size_t)h * 128;
    float q1 = bf2f(QKV[base + i]);
    float q2 = bf2f(QKV[base + i + 64]);
    float c1 = cosb[s * 128 + i],      s1 = sinb[s * 128 + i];
    float c2 = cosb[s * 128 + i + 64], s2 = sinb[s * 128 + i + 64];
    QKV[base + i]      = f2bf(q1 * c1 - q2 * s1);
    QKV[base + i + 64] = f2bf(q2 * c2 + q1 * s2);
    return;
  }
  // ---- V transpose: qkv V cols -> Vt_g[kvh*128+hd][s] ----
  __shared__ unsigned short t[32][33];
  const int b  = bxg - 20480;
  const int s0 = (b & 63) * 32;           // 64 s-tiles
  const int c0 = (b >> 6) * 32;           // 32 c-tiles
  int x = tid & 31, y4 = (tid >> 5) * 4;
#pragma unroll
  for (int i = 0; i < 4; ++i)
    t[y4 + i][x] = QKV[(size_t)(s0 + y4 + i) * NQKV + VOFF + c0 + x];
  __syncthreads();
#pragma unroll
  for (int i = 0; i < 4; ++i)
    Vt_g[(size_t)(c0 + y4 + i) * SEQ + s0 + x] = t[x][y4 + i];
}

// ---------------- flash attention: S^T formulation (unchanged) ----------------
__global__ __launch_bounds__(256) void flash_attn(const unsigned short* __restrict__ QKV,
                                                  const unsigned short* __restrict__ Vt_g,
                                                  unsigned short* __restrict__ AO) {
  __shared__ unsigned short Ks[64 * 136];
  __shared__ unsigned short Vs[128 * 72];
  __shared__ unsigned short Ps[4][32 * 68];

  const int h   = blockIdx.x;
  const int qt  = (int)gridDim.y - 1 - (int)blockIdx.y;
  const int kvh = h >> 2;
  const int tid  = threadIdx.x;
  const int w    = tid >> 6;
  const int lane = tid & 63;
  const int l16  = lane & 15;
  const int quad = lane >> 4;
  const int q0   = qt * 128;
  const int qrow_w = q0 + w * 32;

  short8 qf[2][4];
#pragma unroll
  for (int ntq = 0; ntq < 2; ++ntq) {
    const unsigned short* qp = QKV + (size_t)(qrow_w + ntq * 16 + l16) * NQKV + h * HD + quad * 8;
#pragma unroll
    for (int ks = 0; ks < 4; ++ks) qf[ntq][ks] = *(const short8*)(qp + ks * 32);
  }

  f32x4 o[8][2];
#pragma unroll
  for (int i = 0; i < 8; ++i) { o[i][0] = (f32x4){0,0,0,0}; o[i][1] = (f32x4){0,0,0,0}; }
  float m_i[2] = {-3.0e38f, -3.0e38f}, l_i[2] = {0.f, 0.f};

  const int kr = tid >> 2, kcol0 = (tid & 3) * 32;
  const int vr = tid >> 1, vcol0 = (tid & 1) * 32;
  const unsigned short* kbase = QKV + KOFF + (size_t)kvh * HD + kcol0;
  const unsigned short* vbase = Vt_g + ((size_t)kvh * HD + vr) * SEQ + vcol0;

  const int nch = qt * 2 + 2;
  for (int c = 0; c < nch; ++c) {
    const int kc = c * 64;
    short8 kv[4], vv[4];
#pragma unroll
    for (int u = 0; u < 4; ++u) kv[u] = *(const short8*)(kbase + (size_t)(kc + kr) * NQKV + u * 8);
#pragma unroll
    for (int u = 0; u < 4; ++u) vv[u] = *(const short8*)(vbase + kc + u * 8);
    __syncthreads();
#pragma unroll
    for (int u = 0; u < 4; ++u) *(short8*)&Ks[kr * 136 + kcol0 + u * 8] = kv[u];
#pragma unroll
    for (int u = 0; u < 4; ++u) *(short8*)&Vs[vr * 72 + vcol0 + u * 8] = vv[u];
    __syncthreads();

    if (kc <= qrow_w + 31) {
      f32x4 st[4][2];
#pragma unroll
      for (int mt = 0; mt < 4; ++mt) { st[mt][0] = (f32x4){0,0,0,0}; st[mt][1] = (f32x4){0,0,0,0}; }
#pragma unroll
      for (int ks = 0; ks < 4; ++ks)
#pragma unroll
        for (int mt = 0; mt < 4; ++mt) {
          short8 ak = *(const short8*)&Ks[(mt * 16 + l16) * 136 + ks * 32 + quad * 8];
          st[mt][0] = __builtin_amdgcn_mfma_f32_16x16x32_bf16(ak, qf[0][ks], st[mt][0], 0, 0, 0);
          st[mt][1] = __builtin_amdgcn_mfma_f32_16x16x32_bf16(ak, qf[1][ks], st[mt][1], 0, 0, 0);
        }

      float sc[4][2][4];
#pragma unroll
      for (int mt = 0; mt < 4; ++mt)
#pragma unroll
        for (int ntq = 0; ntq < 2; ++ntq) {
          int qr = qrow_w + ntq * 16 + l16;
#pragma unroll
          for (int r = 0; r < 4; ++r) {
            int key = kc + mt * 16 + quad * 4 + r;
            float v = st[mt][ntq][r] * SCALE;
            sc[mt][ntq][r] = (key <= qr) ? v : -__builtin_inff();
          }
        }
      float mx[2] = {-__builtin_inff(), -__builtin_inff()};
#pragma unroll
      for (int mt = 0; mt < 4; ++mt)
#pragma unroll
        for (int ntq = 0; ntq < 2; ++ntq)
#pragma unroll
          for (int r = 0; r < 4; ++r) mx[ntq] = fmaxf(mx[ntq], sc[mt][ntq][r]);
#pragma unroll
      for (int ntq = 0; ntq < 2; ++ntq) {
        mx[ntq] = fmaxf(mx[ntq], __shfl_xor(mx[ntq], 16, 64));
        mx[ntq] = fmaxf(mx[ntq], __shfl_xor(mx[ntq], 32, 64));
      }
      float al[2], mn[2];
#pragma unroll
      for (int ntq = 0; ntq < 2; ++ntq) {
        mn[ntq] = fmaxf(m_i[ntq], mx[ntq]);
        al[ntq] = __expf(m_i[ntq] - mn[ntq]);
        m_i[ntq] = mn[ntq];
      }

      float rs[2] = {0.f, 0.f};
      unsigned short* psw = &Ps[w][0];
#pragma unroll
      for (int mt = 0; mt < 4; ++mt)
#pragma unroll
        for (int ntq = 0; ntq < 2; ++ntq) {
          float p0 = __expf(sc[mt][ntq][0] - mn[ntq]);
          float p1 = __expf(sc[mt][ntq][1] - mn[ntq]);
          float p2 = __expf(sc[mt][ntq][2] - mn[ntq]);
          float p3 = __expf(sc[mt][ntq][3] - mn[ntq]);
          rs[ntq] += (p0 + p1) + (p2 + p3);
          ushort4 pk; pk.x = f2bf(p0); pk.y = f2bf(p1); pk.z = f2bf(p2); pk.w = f2bf(p3);
          *(ushort4*)&psw[(ntq * 16 + l16) * 68 + mt * 16 + quad * 4] = pk;
        }
#pragma unroll
      for (int ntq = 0; ntq < 2; ++ntq) {
        rs[ntq] += __shfl_xor(rs[ntq], 16, 64);
        rs[ntq] += __shfl_xor(rs[ntq], 32, 64);
        l_i[ntq] = l_i[ntq] * al[ntq] + rs[ntq];
      }
#pragma unroll
      for (int i = 0; i < 8; ++i) {
        o[i][0][0] *= al[0]; o[i][0][1] *= al[0]; o[i][0][2] *= al[0]; o[i][0][3] *= al[0];
        o[i][1][0] *= al[1]; o[i][1][1] *= al[1]; o[i][1][2] *= al[1]; o[i][1][3] *= al[1];
      }

#pragma unroll
      for (int ks = 0; ks < 2; ++ks) {
        short8 bp[2];
#pragma unroll
        for (int ntq = 0; ntq < 2; ++ntq) {
          union { ushort4 h[2]; short8 v; } u;
          const unsigned short* pp = &psw[(ntq * 16 + l16) * 68 + ks * 32 + quad * 8];
          u.h[0] = *(const ushort4*)(pp);
          u.h[1] = *(const ushort4*)(pp + 4);
          bp[ntq] = u.v;
        }
#pragma unroll
        for (int mt = 0; mt < 8; ++mt) {
          short8 av = *(const short8*)&Vs[(mt * 16 + l16) * 72 + ks * 32 + quad * 8];
          o[mt][0] = __builtin_amdgcn_mfma_f32_16x16x32_bf16(av, bp[0], o[mt][0], 0, 0, 0);
          o[mt][1] = __builtin_amdgcn_mfma_f32_16x16x32_bf16(av, bp[1], o[mt][1], 0, 0, 0);
        }
      }
    }
  }

  float inv[2] = {1.0f / l_i[0], 1.0f / l_i[1]};
#pragma unroll
  for (int mt = 0; mt < 8; ++mt)
#pragma unroll
    for (int ntq = 0; ntq < 2; ++ntq) {
      int qr = qrow_w + ntq * 16 + l16;
      int col = h * HD + mt * 16 + quad * 4;
      ushort4 ov;
      ov.x = f2bf(o[mt][ntq][0] * inv[ntq]);
      ov.y = f2bf(o[mt][ntq][1] * inv[ntq]);
      ov.z = f2bf(o[mt][ntq][2] * inv[ntq]);
      ov.w = f2bf(o[mt][ntq][3] * inv[ntq]);
      *(ushort4*)&AO[(size_t)qr * DM + col] = ov;
    }
}

extern "C" void kernel_launch(void* const* d_in, const int* in_sizes, int n_in,
                              void* d_out, int out_size, void* d_ws, size_t ws_size,
                              hipStream_t stream) {
  const float* hs   = (const float*)d_in[0];
  const float* cosb = (const float*)d_in[1];
  const float* sinb = (const float*)d_in[2];
  // d_in[3] attention_mask: all ones -> causal-only
  const float* wq = (const float*)d_in[4];
  const float* wk = (const float*)d_in[5];
  const float* wv = (const float*)d_in[6];
  const float* wo = (const float*)d_in[7];
  float* out = (float*)d_out;

  char* ws = (char*)d_ws;
  unsigned short* hsb   = (unsigned short*)(ws);                 // 16 MB (reused as Vt_g later)
  unsigned short* wqkvT = (unsigned short*)(ws + (16u << 20));   // 48 MB
  unsigned short* woT   = (unsigned short*)(ws + (64u << 20));   // 32 MB
  unsigned short* qkv   = (unsigned short*)(ws + (96u << 20));   // 24 MB
  unsigned short* ao    = (unsigned short*)(ws + (120u << 20));  // 16 MB
  unsigned short* Vt_g  = hsb;   // 4 MB; hsb is dead after the QKV GEMM

  prep<<<8192 + 160 * 64, 256, 0, stream>>>(hs, wq, wk, wv, wo, hsb, wqkvT, woT);
  gemm_bt<<<dim3(NQKV / 128, SEQ / 64), 256, 0, stream>>>(hsb, wqkvT, qkv, SEQ, NQKV, DM, 0);
  rope_vt<<<20480 + 2048, 256, 0, stream>>>(qkv, cosb, sinb, Vt_g);
  flash_attn<<<dim3(NH, SEQ / 128), 256, 0, stream>>>(qkv, Vt_g, ao);
  gemm_bt<<<dim3(DM / 128, SEQ / 64), 256, 0, stream>>>(ao, woT, out, SEQ, DM, DM, 1);
}

// Round 7
// 535.170 us; speedup vs baseline: 1.1030x; 1.1030x over previous
//
#include <hip/hip_runtime.h>
#include <hip/hip_bf16.h>

// Problem constants (B=1)
#define SEQ   2048
#define DM    4096
#define NH    32
#define NKVH  8
#define HD    128
#define NQKV  6144
#define KOFF  4096
#define VOFF  5120
#define QLD   5120     // qkv row stride: V cols not materialized row-major
#define SCALE 0.08838834764831845f

typedef __attribute__((ext_vector_type(4))) float f32x4;
typedef __attribute__((ext_vector_type(8))) short short8;

__device__ __forceinline__ unsigned short f2bf(float f) {
  union { float f; unsigned int u; } v; v.f = f;
  unsigned int r = v.u + 0x7FFF + ((v.u >> 16) & 1);
  return (unsigned short)(r >> 16);
}
__device__ __forceinline__ float bf2f(unsigned short b) {
  union { unsigned int u; float f; } v; v.u = ((unsigned int)b) << 16;
  return v.f;
}

// async global->LDS, 16B per lane; LDS dest = wave-uniform base + lane*16
__device__ __forceinline__ void gld16(const unsigned short* g, unsigned short* l) {
  __builtin_amdgcn_global_load_lds(
      (const __attribute__((address_space(1))) unsigned int*)g,
      (__attribute__((address_space(3))) unsigned int*)l, 16, 0, 0);
}

// ---------------- fused prep: hs cast (blocks 0..8191) + weight transpose ----------------
__global__ __launch_bounds__(256) void prep(const float* __restrict__ hs,
                                            const float* __restrict__ wq,
                                            const float* __restrict__ wk,
                                            const float* __restrict__ wv,
                                            const float* __restrict__ wo,
                                            unsigned short* __restrict__ hsb,
                                            unsigned short* __restrict__ wqkvT,
                                            unsigned short* __restrict__ woT) {
  __shared__ unsigned short t[64][68];
  const int bxg = blockIdx.x;
  const int tid = threadIdx.x;
  if (bxg < 8192) {                       // ---- cast hs fp32 -> bf16 ----
    size_t i = ((size_t)bxg * 256 + tid) * 4;
    float4 v = *(const float4*)(hs + i);
    ushort4 o;
    o.x = f2bf(v.x); o.y = f2bf(v.y); o.z = f2bf(v.z); o.w = f2bf(v.w);
    *(ushort4*)(hsb + i) = o;
    return;
  }
  // ---- weight transpose+cast, 64x64 tiles ----
  const int b  = bxg - 8192;
  const int bx = b % 160;
  const int k0 = (b / 160) * 64;
  const float* W; unsigned short* out; int N, n0, row_off;
  if (bx < 64)      { W = wq; out = wqkvT; N = 4096; n0 = bx * 64;        row_off = 0;    }
  else if (bx < 80) { W = wk; out = wqkvT; N = 1024; n0 = (bx - 64) * 64; row_off = 4096; }
  else if (bx < 96) { W = wv; out = wqkvT; N = 1024; n0 = (bx - 80) * 64; row_off = 5120; }
  else              { W = wo; out = woT;   N = 4096; n0 = (bx - 96) * 64; row_off = 0;    }

  const int lr = tid >> 4, lc = (tid & 15) * 4;
#pragma unroll
  for (int i = 0; i < 4; ++i) {
    float4 v = *(const float4*)&W[(size_t)(k0 + lr + i * 16) * N + n0 + lc];
    ushort4 u; u.x = f2bf(v.x); u.y = f2bf(v.y); u.z = f2bf(v.z); u.w = f2bf(v.w);
    *(ushort4*)&t[lr + i * 16][lc] = u;
  }
  __syncthreads();

  const int sn = tid >> 2, sk = (tid & 3) * 4;
#pragma unroll
  for (int i = 0; i < 4; ++i) {
    int kk = sk + i * 16;
    ushort4 u;
    u.x = t[kk + 0][sn]; u.y = t[kk + 1][sn];
    u.z = t[kk + 2][sn]; u.w = t[kk + 3][sn];
    *(ushort4*)&out[(size_t)(row_off + n0 + sn) * DM + k0 + kk] = u;
  }
}

// ---------------- GEMM: C[M,N] = A[M,K] @ Bt[N,K]^T ----------------
// R5 config: 128x128 tile, BK=32, double-buffered gld16 (1 barrier/iter),
// coalesced staging (4 lanes per 64B row-slice), XOR k-block LDS swizzle.
// If vt != null, column-blocks with n0 >= VOFF write TRANSPOSED to
// vt[(col-VOFF)*SEQ + row] (C-layout's 4 consecutive rows -> one ushort4),
// eliminating the separate V-transpose pass. ldc decouples C stride from N.
__global__ __launch_bounds__(256) void gemm_bt(const unsigned short* __restrict__ A,
                                               const unsigned short* __restrict__ Bt,
                                               void* __restrict__ C,
                                               unsigned short* __restrict__ vt,
                                               int M, int N, int K, int ldc, int c_fp32) {
  __shared__ unsigned short As[2][128 * 32];
  __shared__ unsigned short Bs[2][128 * 32];
  const int tid  = threadIdx.x;
  const int m0   = blockIdx.y * 128;
  const int n0   = blockIdx.x * 128;
  const int w    = tid >> 6;
  const int lane = tid & 63;
  const int l16  = lane & 15;
  const int quad = lane >> 4;
  const int wr   = (w >> 1) * 64;
  const int wc   = (w & 1) * 64;

  f32x4 acc[4][4];
#pragma unroll
  for (int i = 0; i < 4; ++i)
#pragma unroll
    for (int j = 0; j < 4; ++j) acc[i][j] = (f32x4){0.f, 0.f, 0.f, 0.f};

  const int sr  = lane >> 2;
  const int pb  = lane & 3;
  const int sws = (sr & 3) ^ ((sr >> 2) & 3);
  const int kb  = ((pb ^ sws) << 3);
  const unsigned short* ga0 = A  + (size_t)(m0 + w * 16 + sr) * K + kb;
  const unsigned short* ga1 = A  + (size_t)(m0 + 64 + w * 16 + sr) * K + kb;
  const unsigned short* gb0 = Bt + (size_t)(n0 + w * 16 + sr) * K + kb;
  const unsigned short* gb1 = Bt + (size_t)(n0 + 64 + w * 16 + sr) * K + kb;
  const int lofs0 = (w * 16) * 32;
  const int lofs1 = (64 + w * 16) * 32;

  const int swf  = (l16 & 3) ^ ((l16 >> 2) & 3);
  const int fcol = ((quad ^ swf) << 3);

  gld16(ga0, &As[0][lofs0]);
  gld16(ga1, &As[0][lofs1]);
  gld16(gb0, &Bs[0][lofs0]);
  gld16(gb1, &Bs[0][lofs1]);

  int p = 0;
  for (int k0 = 0; k0 < K; k0 += 32) {
    __syncthreads();            // drains vmcnt -> buf p visible; buf p^1 WAR-safe
    if (k0 + 32 < K) {
      gld16(ga0 + k0 + 32, &As[p ^ 1][lofs0]);
      gld16(ga1 + k0 + 32, &As[p ^ 1][lofs1]);
      gld16(gb0 + k0 + 32, &Bs[p ^ 1][lofs0]);
      gld16(gb1 + k0 + 32, &Bs[p ^ 1][lofs1]);
    }
    short8 af[4], bfr[4];
#pragma unroll
    for (int mt = 0; mt < 4; ++mt)
      af[mt] = *(const short8*)&As[p][(wr + mt * 16 + l16) * 32 + fcol];
#pragma unroll
    for (int nt = 0; nt < 4; ++nt)
      bfr[nt] = *(const short8*)&Bs[p][(wc + nt * 16 + l16) * 32 + fcol];
#pragma unroll
    for (int mt = 0; mt < 4; ++mt)
#pragma unroll
      for (int nt = 0; nt < 4; ++nt)
        acc[mt][nt] = __builtin_amdgcn_mfma_f32_16x16x32_bf16(af[mt], bfr[nt], acc[mt][nt], 0, 0, 0);
    p ^= 1;
  }

  if (vt && n0 >= VOFF) {       // V block: transposed bf16 store vt[col][row]
#pragma unroll
    for (int mt = 0; mt < 4; ++mt)
#pragma unroll
      for (int nt = 0; nt < 4; ++nt) {
        int col  = (n0 - VOFF) + wc + nt * 16 + l16;
        int row0 = m0 + wr + mt * 16 + quad * 4;
        ushort4 ov;
        ov.x = f2bf(acc[mt][nt][0]); ov.y = f2bf(acc[mt][nt][1]);
        ov.z = f2bf(acc[mt][nt][2]); ov.w = f2bf(acc[mt][nt][3]);
        *(ushort4*)&vt[(size_t)col * SEQ + row0] = ov;
      }
  } else if (c_fp32) {
    float* Cf = (float*)C;
#pragma unroll
    for (int mt = 0; mt < 4; ++mt)
#pragma unroll
      for (int nt = 0; nt < 4; ++nt) {
        int col = n0 + wc + nt * 16 + l16;
#pragma unroll
        for (int r = 0; r < 4; ++r)
          Cf[(size_t)(m0 + wr + mt * 16 + quad * 4 + r) * ldc + col] = acc[mt][nt][r];
      }
  } else {
    unsigned short* Cb = (unsigned short*)C;
#pragma unroll
    for (int mt = 0; mt < 4; ++mt)
#pragma unroll
      for (int nt = 0; nt < 4; ++nt) {
        int col = n0 + wc + nt * 16 + l16;
#pragma unroll
        for (int r = 0; r < 4; ++r)
          Cb[(size_t)(m0 + wr + mt * 16 + quad * 4 + r) * ldc + col] = f2bf(acc[mt][nt][r]);
      }
  }
}

// ---------------- RoPE in-place on qkv (stride QLD), heads 0..39 = 32 q + 8 k ----------------
__global__ __launch_bounds__(256) void rope_kernel(unsigned short* __restrict__ QKV,
                                                   const float* __restrict__ cosb,
                                                   const float* __restrict__ sinb) {
  int idx = blockIdx.x * 256 + threadIdx.x;
  int i = idx & 63;
  int h = (idx >> 6) % 40;
  int s = idx / 2560;
  size_t base = (size_t)s * QLD + (size_t)h * 128;
  float q1 = bf2f(QKV[base + i]);
  float q2 = bf2f(QKV[base + i + 64]);
  float c1 = cosb[s * 128 + i],      s1 = sinb[s * 128 + i];
  float c2 = cosb[s * 128 + i + 64], s2 = sinb[s * 128 + i + 64];
  QKV[base + i]      = f2bf(q1 * c1 - q2 * s1);
  QKV[base + i + 64] = f2bf(q2 * c2 + q1 * s2);
}

// ---------------- flash attention: S^T formulation (QLD stride) ----------------
__global__ __launch_bounds__(256) void flash_attn(const unsigned short* __restrict__ QKV,
                                                  const unsigned short* __restrict__ Vt_g,
                                                  unsigned short* __restrict__ AO) {
  __shared__ unsigned short Ks[64 * 136];
  __shared__ unsigned short Vs[128 * 72];
  __shared__ unsigned short Ps[4][32 * 68];

  const int h   = blockIdx.x;
  const int qt  = (int)gridDim.y - 1 - (int)blockIdx.y;
  const int kvh = h >> 2;
  const int tid  = threadIdx.x;
  const int w    = tid >> 6;
  const int lane = tid & 63;
  const int l16  = lane & 15;
  const int quad = lane >> 4;
  const int q0   = qt * 128;
  const int qrow_w = q0 + w * 32;

  short8 qf[2][4];
#pragma unroll
  for (int ntq = 0; ntq < 2; ++ntq) {
    const unsigned short* qp = QKV + (size_t)(qrow_w + ntq * 16 + l16) * QLD + h * HD + quad * 8;
#pragma unroll
    for (int ks = 0; ks < 4; ++ks) qf[ntq][ks] = *(const short8*)(qp + ks * 32);
  }

  f32x4 o[8][2];
#pragma unroll
  for (int i = 0; i < 8; ++i) { o[i][0] = (f32x4){0,0,0,0}; o[i][1] = (f32x4){0,0,0,0}; }
  float m_i[2] = {-3.0e38f, -3.0e38f}, l_i[2] = {0.f, 0.f};

  const int kr = tid >> 2, kcol0 = (tid & 3) * 32;
  const int vr = tid >> 1, vcol0 = (tid & 1) * 32;
  const unsigned short* kbase = QKV + KOFF + (size_t)kvh * HD + kcol0;
  const unsigned short* vbase = Vt_g + ((size_t)kvh * HD + vr) * SEQ + vcol0;

  const int nch = qt * 2 + 2;
  for (int c = 0; c < nch; ++c) {
    const int kc = c * 64;
    short8 kv[4], vv[4];
#pragma unroll
    for (int u = 0; u < 4; ++u) kv[u] = *(const short8*)(kbase + (size_t)(kc + kr) * QLD + u * 8);
#pragma unroll
    for (int u = 0; u < 4; ++u) vv[u] = *(const short8*)(vbase + kc + u * 8);
    __syncthreads();
#pragma unroll
    for (int u = 0; u < 4; ++u) *(short8*)&Ks[kr * 136 + kcol0 + u * 8] = kv[u];
#pragma unroll
    for (int u = 0; u < 4; ++u) *(short8*)&Vs[vr * 72 + vcol0 + u * 8] = vv[u];
    __syncthreads();

    if (kc <= qrow_w + 31) {
      f32x4 st[4][2];
#pragma unroll
      for (int mt = 0; mt < 4; ++mt) { st[mt][0] = (f32x4){0,0,0,0}; st[mt][1] = (f32x4){0,0,0,0}; }
#pragma unroll
      for (int ks = 0; ks < 4; ++ks)
#pragma unroll
        for (int mt = 0; mt < 4; ++mt) {
          short8 ak = *(const short8*)&Ks[(mt * 16 + l16) * 136 + ks * 32 + quad * 8];
          st[mt][0] = __builtin_amdgcn_mfma_f32_16x16x32_bf16(ak, qf[0][ks], st[mt][0], 0, 0, 0);
          st[mt][1] = __builtin_amdgcn_mfma_f32_16x16x32_bf16(ak, qf[1][ks], st[mt][1], 0, 0, 0);
        }

      float sc[4][2][4];
#pragma unroll
      for (int mt = 0; mt < 4; ++mt)
#pragma unroll
        for (int ntq = 0; ntq < 2; ++ntq) {
          int qr = qrow_w + ntq * 16 + l16;
#pragma unroll
          for (int r = 0; r < 4; ++r) {
            int key = kc + mt * 16 + quad * 4 + r;
            float v = st[mt][ntq][r] * SCALE;
            sc[mt][ntq][r] = (key <= qr) ? v : -__builtin_inff();
          }
        }
      float mx[2] = {-__builtin_inff(), -__builtin_inff()};
#pragma unroll
      for (int mt = 0; mt < 4; ++mt)
#pragma unroll
        for (int ntq = 0; ntq < 2; ++ntq)
#pragma unroll
          for (int r = 0; r < 4; ++r) mx[ntq] = fmaxf(mx[ntq], sc[mt][ntq][r]);
#pragma unroll
      for (int ntq = 0; ntq < 2; ++ntq) {
        mx[ntq] = fmaxf(mx[ntq], __shfl_xor(mx[ntq], 16, 64));
        mx[ntq] = fmaxf(mx[ntq], __shfl_xor(mx[ntq], 32, 64));
      }
      float al[2], mn[2];
#pragma unroll
      for (int ntq = 0; ntq < 2; ++ntq) {
        mn[ntq] = fmaxf(m_i[ntq], mx[ntq]);
        al[ntq] = __expf(m_i[ntq] - mn[ntq]);
        m_i[ntq] = mn[ntq];
      }

      float rs[2] = {0.f, 0.f};
      unsigned short* psw = &Ps[w][0];
#pragma unroll
      for (int mt = 0; mt < 4; ++mt)
#pragma unroll
        for (int ntq = 0; ntq < 2; ++ntq) {
          float p0 = __expf(sc[mt][ntq][0] - mn[ntq]);
          float p1 = __expf(sc[mt][ntq][1] - mn[ntq]);
          float p2 = __expf(sc[mt][ntq][2] - mn[ntq]);
          float p3 = __expf(sc[mt][ntq][3] - mn[ntq]);
          rs[ntq] += (p0 + p1) + (p2 + p3);
          ushort4 pk; pk.x = f2bf(p0); pk.y = f2bf(p1); pk.z = f2bf(p2); pk.w = f2bf(p3);
          *(ushort4*)&psw[(ntq * 16 + l16) * 68 + mt * 16 + quad * 4] = pk;
        }
#pragma unroll
      for (int ntq = 0; ntq < 2; ++ntq) {
        rs[ntq] += __shfl_xor(rs[ntq], 16, 64);
        rs[ntq] += __shfl_xor(rs[ntq], 32, 64);
        l_i[ntq] = l_i[ntq] * al[ntq] + rs[ntq];
      }
#pragma unroll
      for (int i = 0; i < 8; ++i) {
        o[i][0][0] *= al[0]; o[i][0][1] *= al[0]; o[i][0][2] *= al[0]; o[i][0][3] *= al[0];
        o[i][1][0] *= al[1]; o[i][1][1] *= al[1]; o[i][1][2] *= al[1]; o[i][1][3] *= al[1];
      }

#pragma unroll
      for (int ks = 0; ks < 2; ++ks) {
        short8 bp[2];
#pragma unroll
        for (int ntq = 0; ntq < 2; ++ntq) {
          union { ushort4 h[2]; short8 v; } u;
          const unsigned short* pp = &psw[(ntq * 16 + l16) * 68 + ks * 32 + quad * 8];
          u.h[0] = *(const ushort4*)(pp);
          u.h[1] = *(const ushort4*)(pp + 4);
          bp[ntq] = u.v;
        }
#pragma unroll
        for (int mt = 0; mt < 8; ++mt) {
          short8 av = *(const short8*)&Vs[(mt * 16 + l16) * 72 + ks * 32 + quad * 8];
          o[mt][0] = __builtin_amdgcn_mfma_f32_16x16x32_bf16(av, bp[0], o[mt][0], 0, 0, 0);
          o[mt][1] = __builtin_amdgcn_mfma_f32_16x16x32_bf16(av, bp[1], o[mt][1], 0, 0, 0);
        }
      }
    }
  }

  float inv[2] = {1.0f / l_i[0], 1.0f / l_i[1]};
#pragma unroll
  for (int mt = 0; mt < 8; ++mt)
#pragma unroll
    for (int ntq = 0; ntq < 2; ++ntq) {
      int qr = qrow_w + ntq * 16 + l16;
      int col = h * HD + mt * 16 + quad * 4;
      ushort4 ov;
      ov.x = f2bf(o[mt][ntq][0] * inv[ntq]);
      ov.y = f2bf(o[mt][ntq][1] * inv[ntq]);
      ov.z = f2bf(o[mt][ntq][2] * inv[ntq]);
      ov.w = f2bf(o[mt][ntq][3] * inv[ntq]);
      *(ushort4*)&AO[(size_t)qr * DM + col] = ov;
    }
}

extern "C" void kernel_launch(void* const* d_in, const int* in_sizes, int n_in,
                              void* d_out, int out_size, void* d_ws, size_t ws_size,
                              hipStream_t stream) {
  const float* hs   = (const float*)d_in[0];
  const float* cosb = (const float*)d_in[1];
  const float* sinb = (const float*)d_in[2];
  // d_in[3] attention_mask: all ones -> causal-only
  const float* wq = (const float*)d_in[4];
  const float* wk = (const float*)d_in[5];
  const float* wv = (const float*)d_in[6];
  const float* wo = (const float*)d_in[7];
  float* out = (float*)d_out;

  char* ws = (char*)d_ws;
  unsigned short* hsb   = (unsigned short*)(ws);                 // 16 MB
  unsigned short* wqkvT = (unsigned short*)(ws + (16u << 20));   // 48 MB
  unsigned short* woT   = (unsigned short*)(ws + (64u << 20));   // 32 MB
  unsigned short* qkv   = (unsigned short*)(ws + (96u << 20));   // 20 MB (2048 x 5120, Q+K only)
  unsigned short* ao    = (unsigned short*)(ws + (116u << 20));  // 16 MB
  unsigned short* Vt_g  = (unsigned short*)(ws + (132u << 20));  // 4 MB (distinct: gemm writes it while reading hsb)

  prep<<<8192 + 160 * 64, 256, 0, stream>>>(hs, wq, wk, wv, wo, hsb, wqkvT, woT);
  gemm_bt<<<dim3(NQKV / 128, SEQ / 128), 256, 0, stream>>>(hsb, wqkvT, qkv, Vt_g, SEQ, NQKV, DM, QLD, 0);
  rope_kernel<<<20480, 256, 0, stream>>>(qkv, cosb, sinb);
  flash_attn<<<dim3(NH, SEQ / 128), 256, 0, stream>>>(qkv, Vt_g, ao);
  gemm_bt<<<dim3(DM / 128, SEQ / 128), 256, 0, stream>>>(ao, woT, out, nullptr, SEQ, DM, DM, DM, 1);
}